// Round 1
// baseline (552.864 us; speedup 1.0000x reference)
//
#include <hip/hip_runtime.h>

typedef unsigned short u16;
typedef __attribute__((ext_vector_type(8))) short short8;
typedef __attribute__((ext_vector_type(4))) float f32x4;

#define DIM 512
#define CTX 768
#define HW 4096
#define NB 16
#define NS 256
#define EPSV 1e-5f

__device__ inline u16 f2bf(float f) {
    union { float f; unsigned u; } x; x.f = f;
    unsigned r = x.u + 0x7fffu + ((x.u >> 16) & 1u);
    return (u16)(r >> 16);
}

// ---------------- GroupNorm stats: per (b,g) mean/var -> per-channel a,d ----
__global__ void gn_stats(const float* __restrict__ x, const float* __restrict__ gn_w,
                         const float* __restrict__ gn_b, float* __restrict__ ga,
                         float* __restrict__ gd) {
    const int bg = blockIdx.x;           // b*32 + g
    const int b = bg >> 5, g = bg & 31;
    const float* base = x + ((long)b * DIM + g * 16) * HW;  // 16 chans contiguous = 65536 floats
    float s1 = 0.f, s2 = 0.f;
    const int tid = threadIdx.x;
    for (int i = tid; i < 16384; i += 256) {
        float4 v = ((const float4*)base)[i];
        s1 += v.x + v.y + v.z + v.w;
        s2 += v.x * v.x + v.y * v.y + v.z * v.z + v.w * v.w;
    }
    __shared__ float r1[256], r2[256];
    r1[tid] = s1; r2[tid] = s2; __syncthreads();
    for (int s = 128; s > 0; s >>= 1) {
        if (tid < s) { r1[tid] += r1[tid + s]; r2[tid] += r2[tid + s]; }
        __syncthreads();
    }
    __shared__ float mu_s, rs_s;
    if (tid == 0) {
        float mu = r1[0] * (1.f / 65536.f);
        float var = r2[0] * (1.f / 65536.f) - mu * mu;
        mu_s = mu; rs_s = rsqrtf(var + EPSV);
    }
    __syncthreads();
    if (tid < 16) {
        int c = g * 16 + tid;
        float aa = rs_s * gn_w[c];
        ga[b * DIM + c] = aa;
        gd[b * DIM + c] = gn_b[c] - mu_s * aa;
    }
}

// ------------- GN apply + transpose: x(b,c,p) -> xn_t(b,p,c) bf16 ----------
__global__ void gn_apply_t(const float* __restrict__ x, const float* __restrict__ ga,
                           const float* __restrict__ gd, u16* __restrict__ xnt) {
    const int b = blockIdx.y;
    const int c0 = (blockIdx.x & 15) * 32;
    const int p0 = (blockIdx.x >> 4) * 32;
    const int tx = threadIdx.x & 31, ty = threadIdx.x >> 5;  // 32 x 8
    __shared__ u16 tile[32][33];
    #pragma unroll
    for (int i = 0; i < 4; i++) {
        int c = c0 + ty + i * 8;
        float v = x[((long)b * DIM + c) * HW + p0 + tx];
        v = v * ga[b * DIM + c] + gd[b * DIM + c];
        tile[ty + i * 8][tx] = f2bf(v);
    }
    __syncthreads();
    #pragma unroll
    for (int i = 0; i < 4; i++) {
        int p = p0 + ty + i * 8;
        xnt[((long)b * HW + p) * DIM + c0 + tx] = tile[tx][ty + i * 8];
    }
}

// ------------- LayerNorm on context -> cn bf16 (b, s, 768) -----------------
__global__ void ln_ctx(const float* __restrict__ ctx, const float* __restrict__ ln_w,
                       const float* __restrict__ ln_b, u16* __restrict__ cn) {
    const int row = blockIdx.x;  // b*256 + s
    const int tid = threadIdx.x;
    const float* r = ctx + (long)row * CTX;
    float v[3]; float s1 = 0.f, s2 = 0.f;
    #pragma unroll
    for (int i = 0; i < 3; i++) { v[i] = r[tid + i * 256]; s1 += v[i]; s2 += v[i] * v[i]; }
    __shared__ float r1[256], r2[256];
    r1[tid] = s1; r2[tid] = s2; __syncthreads();
    for (int s = 128; s > 0; s >>= 1) {
        if (tid < s) { r1[tid] += r1[tid + s]; r2[tid] += r2[tid + s]; }
        __syncthreads();
    }
    __shared__ float mu_s, rs_s;
    if (tid == 0) {
        float mu = r1[0] * (1.f / 768.f);
        float var = r2[0] * (1.f / 768.f) - mu * mu;
        mu_s = mu; rs_s = rsqrtf(var + EPSV);
    }
    __syncthreads();
    #pragma unroll
    for (int i = 0; i < 3; i++) {
        int idx = tid + i * 256;
        cn[(long)row * CTX + idx] = f2bf((v[i] - mu_s) * rs_s * ln_w[idx] + ln_b[idx]);
    }
}

// ------------- weights fp32 -> bf16 ----------------------------------------
__global__ void cvt_weights(const float* __restrict__ wq, const float* __restrict__ wkv,
                            const float* __restrict__ wo, u16* __restrict__ wqb,
                            u16* __restrict__ wkvb, u16* __restrict__ wob) {
    int i = blockIdx.x * 256 + threadIdx.x;
    if (i < 262144) { wqb[i] = f2bf(wq[i]); wob[i] = f2bf(wo[i]); }
    if (i < 786432) wkvb[i] = f2bf(wkv[i]);
}

// ------------- generic 128x128 bf16 MFMA GEMM: C = A(MxK) * B(NxK)^T -------
// EPI 0: kv (split k / v_t, +bkv)   1: q (+bq)   2: sim (*scale, fp32 out)
// EPI 3: attn@v (bf16 out)          4: final (+bo +x, fp32 out)
template <int EPI>
__launch_bounds__(256, 2)
__global__ void gemm_nt(const u16* __restrict__ A, const u16* __restrict__ Bm,
                        const float* __restrict__ bias, const float* __restrict__ xres,
                        void* __restrict__ out0, void* __restrict__ out1,
                        int M, int N, int K, long batchA, long batchB) {
    __shared__ u16 As[128][56];
    __shared__ u16 Bs[128][56];
    const int tid = threadIdx.x;
    const int lane = tid & 63;
    const int wave = tid >> 6;
    const int bb = blockIdx.y;
    const int tiles_n = N >> 7;
    const int m0 = (blockIdx.x / tiles_n) << 7;
    const int n0 = (blockIdx.x % tiles_n) << 7;
    const u16* Ab = A + (long)bb * batchA + (long)m0 * K;
    const u16* Bb = Bm + (long)bb * batchB + (long)n0 * K;

    const int sr = tid >> 2;          // 0..63
    const int sc = (tid & 3) << 3;    // 0,8,16,24
    const int l16 = lane & 15;
    const int quad = lane >> 4;
    const int wr = (wave >> 1) << 6;
    const int wc = (wave & 1) << 6;

    f32x4 acc[4][4] = {};

    for (int k0 = 0; k0 < K; k0 += 32) {
        __syncthreads();
        *(short8*)&As[sr][sc]      = *(const short8*)(Ab + (long)sr * K + k0 + sc);
        *(short8*)&As[sr + 64][sc] = *(const short8*)(Ab + (long)(sr + 64) * K + k0 + sc);
        *(short8*)&Bs[sr][sc]      = *(const short8*)(Bb + (long)sr * K + k0 + sc);
        *(short8*)&Bs[sr + 64][sc] = *(const short8*)(Bb + (long)(sr + 64) * K + k0 + sc);
        __syncthreads();
        short8 af[4], bfr[4];
        #pragma unroll
        for (int i = 0; i < 4; i++) af[i] = *(const short8*)&As[wr + i * 16 + l16][quad * 8];
        #pragma unroll
        for (int j = 0; j < 4; j++) bfr[j] = *(const short8*)&Bs[wc + j * 16 + l16][quad * 8];
        #pragma unroll
        for (int i = 0; i < 4; i++)
            #pragma unroll
            for (int j = 0; j < 4; j++)
                acc[i][j] = __builtin_amdgcn_mfma_f32_16x16x32_bf16(af[i], bfr[j], acc[i][j], 0, 0, 0);
    }

    #pragma unroll
    for (int i = 0; i < 4; i++) {
        #pragma unroll
        for (int r = 0; r < 4; r++) {
            const int row = m0 + wr + i * 16 + quad * 4 + r;
            #pragma unroll
            for (int j = 0; j < 4; j++) {
                const int col = n0 + wc + j * 16 + l16;
                float v = acc[i][j][r];
                if (EPI == 0) {
                    v += bias[col];
                    if (col < DIM) ((u16*)out0)[((long)bb * NS + row) * DIM + col] = f2bf(v);
                    else           ((u16*)out1)[((long)bb * DIM + (col - DIM)) * NS + row] = f2bf(v);
                } else if (EPI == 1) {
                    v += bias[col];
                    ((u16*)out0)[((long)bb * HW + row) * DIM + col] = f2bf(v);
                } else if (EPI == 2) {
                    ((float*)out0)[((long)bb * HW + row) * NS + col] = v * 0.04419417382415922f;
                } else if (EPI == 3) {
                    ((u16*)out0)[((long)bb * HW + row) * DIM + col] = f2bf(v);
                } else {
                    v += bias[row] + xres[((long)bb * DIM + row) * HW + col];
                    ((float*)out0)[((long)bb * DIM + row) * HW + col] = v;
                }
            }
        }
    }
}

// ------------- softmax over rows of 256, fp32 in -> bf16 out ---------------
__global__ void softmax_k(const float* __restrict__ sim, u16* __restrict__ attn) {
    const int row = blockIdx.x * 4 + (threadIdx.x >> 6);
    const int lane = threadIdx.x & 63;
    float4 v = ((const float4*)(sim + (long)row * NS))[lane];
    float m = fmaxf(fmaxf(v.x, v.y), fmaxf(v.z, v.w));
    #pragma unroll
    for (int off = 32; off > 0; off >>= 1) m = fmaxf(m, __shfl_xor(m, off));
    float e0 = __expf(v.x - m), e1 = __expf(v.y - m), e2 = __expf(v.z - m), e3 = __expf(v.w - m);
    float s = e0 + e1 + e2 + e3;
    #pragma unroll
    for (int off = 32; off > 0; off >>= 1) s += __shfl_xor(s, off);
    float inv = 1.f / s;
    unsigned long long pk = (unsigned long long)f2bf(e0 * inv)
                          | ((unsigned long long)f2bf(e1 * inv) << 16)
                          | ((unsigned long long)f2bf(e2 * inv) << 32)
                          | ((unsigned long long)f2bf(e3 * inv) << 48);
    *(unsigned long long*)&attn[(long)row * NS + lane * 4] = pk;
}

extern "C" void kernel_launch(void* const* d_in, const int* in_sizes, int n_in,
                              void* d_out, int out_size, void* d_ws, size_t ws_size,
                              hipStream_t stream) {
    const float* x    = (const float*)d_in[0];
    const float* ctx  = (const float*)d_in[1];
    const float* gn_w = (const float*)d_in[2];
    const float* gn_b = (const float*)d_in[3];
    const float* ln_w = (const float*)d_in[4];
    const float* ln_b = (const float*)d_in[5];
    const float* wq   = (const float*)d_in[6];
    const float* bq   = (const float*)d_in[7];
    const float* wkv  = (const float*)d_in[8];
    const float* bkv  = (const float*)d_in[9];
    const float* wo   = (const float*)d_in[10];
    const float* bo   = (const float*)d_in[11];

    char* ws = (char*)d_ws;
    // region A (64 MiB): xn_t bf16, later reused for sim fp32
    u16*   xnt  = (u16*)(ws + 0);
    float* sim  = (float*)(ws + 0);
    // region B (64 MiB): q bf16, later reused for out_attn bf16
    u16*   q    = (u16*)(ws + 67108864);
    u16*   oatt = (u16*)(ws + 67108864);
    u16*   attn = (u16*)(ws + 134217728);   // 32 MiB
    u16*   cn   = (u16*)(ws + 167772160);   // 12 MiB
    u16*   kbf  = (u16*)(ws + 180355072);   // 4 MiB
    u16*   vtbf = (u16*)(ws + 184549376);   // 4 MiB
    u16*   wqb  = (u16*)(ws + 188743680);
    u16*   wkvb = (u16*)(ws + 189267968);
    u16*   wob  = (u16*)(ws + 190840832);
    float* ga   = (float*)(ws + 191365120);
    float* gd   = ga + NB * DIM;

    gn_stats<<<dim3(NB * 32), dim3(256), 0, stream>>>(x, gn_w, gn_b, ga, gd);
    gn_apply_t<<<dim3(2048, NB), dim3(256), 0, stream>>>(x, ga, gd, xnt);
    ln_ctx<<<dim3(NB * NS), dim3(256), 0, stream>>>(ctx, ln_w, ln_b, cn);
    cvt_weights<<<dim3(3072), dim3(256), 0, stream>>>(wq, wkv, wo, wqb, wkvb, wob);

    // kv = cn(256x768) @ wkv^T -> k(b,s,512), v_t(b,512,s)
    gemm_nt<0><<<dim3(2 * 8, NB), dim3(256), 0, stream>>>(
        cn, wkvb, bkv, nullptr, kbf, vtbf, NS, 2 * DIM, CTX, (long)NS * CTX, 0);
    // q = xn_t(4096x512) @ wq^T -> q(b,p,512)
    gemm_nt<1><<<dim3(32 * 4, NB), dim3(256), 0, stream>>>(
        xnt, wqb, bq, nullptr, q, nullptr, HW, DIM, DIM, (long)HW * DIM, 0);
    // sim = q @ k^T * scale -> fp32 (b,p,256) into region A
    gemm_nt<2><<<dim3(32 * 2, NB), dim3(256), 0, stream>>>(
        q, kbf, nullptr, nullptr, sim, nullptr, HW, NS, DIM, (long)HW * DIM, (long)NS * DIM);
    softmax_k<<<dim3(16384), dim3(256), 0, stream>>>(sim, attn);
    // out = attn(4096x256) @ v -> bf16 (b,p,512) into region B
    gemm_nt<3><<<dim3(32 * 4, NB), dim3(256), 0, stream>>>(
        attn, vtbf, nullptr, nullptr, oatt, nullptr, HW, DIM, NS, (long)HW * NS, (long)DIM * NS);
    // out2 = wo(512x512) @ out_attn^T + bo + x -> fp32 d_out (b,c,p)
    gemm_nt<4><<<dim3(4 * 32, NB), dim3(256), 0, stream>>>(
        wob, oatt, bo, x, d_out, nullptr, DIM, HW, DIM, 0, (long)HW * DIM);
}

// Round 2
// 479.528 us; speedup vs baseline: 1.1529x; 1.1529x over previous
//
#include <hip/hip_runtime.h>

typedef unsigned short u16;
typedef __attribute__((ext_vector_type(8))) short short8;
typedef __attribute__((ext_vector_type(4))) float f32x4;

#define DIM 512
#define CTX 768
#define HW 4096
#define NB 16
#define NS 256
#define EPSV 1e-5f

__device__ inline u16 f2bf(float f) {
    union { float f; unsigned u; } x; x.f = f;
    unsigned r = x.u + 0x7fffu + ((x.u >> 16) & 1u);
    return (u16)(r >> 16);
}
__device__ inline float bf2f(u16 v) {
    union { unsigned u; float f; } x; x.u = (unsigned)v << 16; return x.f;
}

// ---------------- GroupNorm stats: per (b,g) mean/var -> per-channel a,d ----
__global__ void gn_stats(const float* __restrict__ x, const float* __restrict__ gn_w,
                         const float* __restrict__ gn_b, float* __restrict__ ga,
                         float* __restrict__ gd) {
    const int bg = blockIdx.x;           // b*32 + g
    const int b = bg >> 5, g = bg & 31;
    const float* base = x + ((long)b * DIM + g * 16) * HW;
    float s1 = 0.f, s2 = 0.f;
    const int tid = threadIdx.x;
    for (int i = tid; i < 16384; i += 256) {
        float4 v = ((const float4*)base)[i];
        s1 += v.x + v.y + v.z + v.w;
        s2 += v.x * v.x + v.y * v.y + v.z * v.z + v.w * v.w;
    }
    __shared__ float r1[256], r2[256];
    r1[tid] = s1; r2[tid] = s2; __syncthreads();
    for (int s = 128; s > 0; s >>= 1) {
        if (tid < s) { r1[tid] += r1[tid + s]; r2[tid] += r2[tid + s]; }
        __syncthreads();
    }
    __shared__ float mu_s, rs_s;
    if (tid == 0) {
        float mu = r1[0] * (1.f / 65536.f);
        float var = r2[0] * (1.f / 65536.f) - mu * mu;
        mu_s = mu; rs_s = rsqrtf(var + EPSV);
    }
    __syncthreads();
    if (tid < 16) {
        int c = g * 16 + tid;
        float aa = rs_s * gn_w[c];
        ga[b * DIM + c] = aa;
        gd[b * DIM + c] = gn_b[c] - mu_s * aa;
    }
}

// ------------- GN apply + transpose: x(b,c,p) -> xn_t(b,p,c) bf16 ----------
__global__ void gn_apply_t(const float* __restrict__ x, const float* __restrict__ ga,
                           const float* __restrict__ gd, u16* __restrict__ xnt) {
    const int b = blockIdx.y;
    const int c0 = (blockIdx.x & 15) * 32;
    const int p0 = (blockIdx.x >> 4) * 32;
    const int tx = threadIdx.x & 31, ty = threadIdx.x >> 5;  // 32 x 8
    __shared__ u16 tile[32][33];
    #pragma unroll
    for (int i = 0; i < 4; i++) {
        int c = c0 + ty + i * 8;
        float v = x[((long)b * DIM + c) * HW + p0 + tx];
        v = v * ga[b * DIM + c] + gd[b * DIM + c];
        tile[ty + i * 8][tx] = f2bf(v);
    }
    __syncthreads();
    #pragma unroll
    for (int i = 0; i < 4; i++) {
        int p = p0 + ty + i * 8;
        xnt[((long)b * HW + p) * DIM + c0 + tx] = tile[tx][ty + i * 8];
    }
}

// ------------- LayerNorm on context -> cn bf16 (b, s, 768) -----------------
__global__ void ln_ctx(const float* __restrict__ ctx, const float* __restrict__ ln_w,
                       const float* __restrict__ ln_b, u16* __restrict__ cn) {
    const int row = blockIdx.x;  // b*256 + s
    const int tid = threadIdx.x;
    const float* r = ctx + (long)row * CTX;
    float v[3]; float s1 = 0.f, s2 = 0.f;
    #pragma unroll
    for (int i = 0; i < 3; i++) { v[i] = r[tid + i * 256]; s1 += v[i]; s2 += v[i] * v[i]; }
    __shared__ float r1[256], r2[256];
    r1[tid] = s1; r2[tid] = s2; __syncthreads();
    for (int s = 128; s > 0; s >>= 1) {
        if (tid < s) { r1[tid] += r1[tid + s]; r2[tid] += r2[tid + s]; }
        __syncthreads();
    }
    __shared__ float mu_s, rs_s;
    if (tid == 0) {
        float mu = r1[0] * (1.f / 768.f);
        float var = r2[0] * (1.f / 768.f) - mu * mu;
        mu_s = mu; rs_s = rsqrtf(var + EPSV);
    }
    __syncthreads();
    #pragma unroll
    for (int i = 0; i < 3; i++) {
        int idx = tid + i * 256;
        cn[(long)row * CTX + idx] = f2bf((v[i] - mu_s) * rs_s * ln_w[idx] + ln_b[idx]);
    }
}

// ------------- weights fp32 -> bf16 (wq transposed: wqt[c][o] = wq[o][c]) ---
__global__ void cvt_weights(const float* __restrict__ wq, const float* __restrict__ wkv,
                            const float* __restrict__ wo, u16* __restrict__ wqtb,
                            u16* __restrict__ wkvb, u16* __restrict__ wob) {
    int i = blockIdx.x * 256 + threadIdx.x;
    if (i < 262144) {
        wqtb[(i & 511) * 512 + (i >> 9)] = f2bf(wq[i]);
        wob[i] = f2bf(wo[i]);
    }
    if (i < 786432) wkvb[i] = f2bf(wkv[i]);
}

// ------------- kbias[b*NS+s] = dot(k[b,s,:], bq) ---------------------------
__global__ void kbias_k(const u16* __restrict__ k, const float* __restrict__ bq,
                        float* __restrict__ kbias) {
    const int row = blockIdx.x;
    const int tid = threadIdx.x;
    const u16* r = k + (long)row * DIM;
    float s = bf2f(r[tid]) * bq[tid] + bf2f(r[tid + 256]) * bq[tid + 256];
    __shared__ float red[256];
    red[tid] = s; __syncthreads();
    for (int st = 128; st > 0; st >>= 1) {
        if (tid < st) red[tid] += red[tid + st];
        __syncthreads();
    }
    if (tid == 0) kbias[row] = red[0];
}

// ------------- generic 128x128 bf16 MFMA GEMM: C = A(MxK) * B(NxK)^T -------
// EPI 0: kv split (k / v row-major, +bkv)
// EPI 2: sim: fp32 out, (acc + kbias[col]) * scale
// EPI 3: plain bf16 row-major
// EPI 5: bf16 transposed write (out[col][row])
// EPI 6: PV final: LDS-transpose, +bo[col]+x, fp32 out (b, c, p)
template <int EPI>
__launch_bounds__(256, 2)
__global__ void gemm_nt(const u16* __restrict__ A, const u16* __restrict__ Bm,
                        const float* __restrict__ bias, const float* __restrict__ xres,
                        void* __restrict__ out0, void* __restrict__ out1,
                        int M, int N, int K, long batchA, long batchB,
                        long obatch, int ldo) {
    __shared__ __align__(16) char smem_raw[2 * 128 * 56 * 2];
    u16 (*As)[56] = (u16(*)[56])smem_raw;
    u16 (*Bs)[56] = (u16(*)[56])(smem_raw + 128 * 56 * 2);
    const int tid = threadIdx.x;
    const int lane = tid & 63;
    const int wave = tid >> 6;
    const int bb = blockIdx.y;
    const int tiles_n = N >> 7;
    const int m0 = (blockIdx.x / tiles_n) << 7;
    const int n0 = (blockIdx.x % tiles_n) << 7;
    const u16* Ab = A + (long)bb * batchA + (long)m0 * K;
    const u16* Bb = Bm + (long)bb * batchB + (long)n0 * K;

    const int sr = tid >> 2;          // 0..63
    const int sc = (tid & 3) << 3;    // 0,8,16,24
    const int l16 = lane & 15;
    const int quad = lane >> 4;
    const int wr = (wave >> 1) << 6;
    const int wc = (wave & 1) << 6;

    f32x4 acc[4][4] = {};

    for (int k0 = 0; k0 < K; k0 += 32) {
        __syncthreads();
        *(short8*)&As[sr][sc]      = *(const short8*)(Ab + (long)sr * K + k0 + sc);
        *(short8*)&As[sr + 64][sc] = *(const short8*)(Ab + (long)(sr + 64) * K + k0 + sc);
        *(short8*)&Bs[sr][sc]      = *(const short8*)(Bb + (long)sr * K + k0 + sc);
        *(short8*)&Bs[sr + 64][sc] = *(const short8*)(Bb + (long)(sr + 64) * K + k0 + sc);
        __syncthreads();
        short8 af[4], bfr[4];
        #pragma unroll
        for (int i = 0; i < 4; i++) af[i] = *(const short8*)&As[wr + i * 16 + l16][quad * 8];
        #pragma unroll
        for (int j = 0; j < 4; j++) bfr[j] = *(const short8*)&Bs[wc + j * 16 + l16][quad * 8];
        #pragma unroll
        for (int i = 0; i < 4; i++)
            #pragma unroll
            for (int j = 0; j < 4; j++)
                acc[i][j] = __builtin_amdgcn_mfma_f32_16x16x32_bf16(af[i], bfr[j], acc[i][j], 0, 0, 0);
    }

    if (EPI == 6) {
        // epilogue: out[b][col][row] = acc + bo[col] + x[b][col][row], fp32,
        // coalesced along row(p) via LDS transpose (4 passes of 32 cols).
        float* lbuf = (float*)smem_raw;   // 32 * 129 * 4 = 16512 B <= 28672
        #pragma unroll
        for (int t = 0; t < 4; t++) {
            __syncthreads();
            const int tw = (t >= 2) ? 64 : 0;
            if (wc == tw) {
                const int j0 = (t & 1) * 2;
                #pragma unroll
                for (int jj = 0; jj < 2; jj++) {
                    const int j = j0 + jj;
                    const int cl = (wc + j * 16 + l16) - t * 32;  // 0..31
                    #pragma unroll
                    for (int i = 0; i < 4; i++)
                        #pragma unroll
                        for (int r = 0; r < 4; r++)
                            lbuf[cl * 129 + wr + i * 16 + quad * 4 + r] = acc[i][j][r];
                }
            }
            __syncthreads();
            const int p4 = (tid & 31) * 4;
            #pragma unroll
            for (int cc = 0; cc < 4; cc++) {
                const int cl = (tid >> 5) + cc * 8;
                const int cg = n0 + t * 32 + cl;
                float v0 = lbuf[cl * 129 + p4];
                float v1 = lbuf[cl * 129 + p4 + 1];
                float v2 = lbuf[cl * 129 + p4 + 2];
                float v3 = lbuf[cl * 129 + p4 + 3];
                const long idx = (long)bb * obatch + (long)cg * ldo + m0 + p4;
                float4 xr = *(const float4*)&xres[idx];
                const float bv = bias[cg];
                float4 ov;
                ov.x = v0 + xr.x + bv; ov.y = v1 + xr.y + bv;
                ov.z = v2 + xr.z + bv; ov.w = v3 + xr.w + bv;
                *(float4*)&((float*)out0)[idx] = ov;
            }
        }
        return;
    }

    #pragma unroll
    for (int i = 0; i < 4; i++) {
        #pragma unroll
        for (int r = 0; r < 4; r++) {
            const int row = m0 + wr + i * 16 + quad * 4 + r;
            #pragma unroll
            for (int j = 0; j < 4; j++) {
                const int col = n0 + wc + j * 16 + l16;
                float v = acc[i][j][r];
                if (EPI == 0) {
                    v += bias[col];
                    if (col < DIM) ((u16*)out0)[(long)bb * obatch + (long)row * ldo + col] = f2bf(v);
                    else           ((u16*)out1)[(long)bb * obatch + (long)row * ldo + (col - DIM)] = f2bf(v);
                } else if (EPI == 2) {
                    v = (v + bias[bb * NS + col]) * 0.04419417382415922f;
                    ((float*)out0)[(long)bb * obatch + (long)row * ldo + col] = v;
                } else if (EPI == 3) {
                    ((u16*)out0)[(long)bb * obatch + (long)row * ldo + col] = f2bf(v);
                } else {  // EPI == 5
                    ((u16*)out0)[(long)bb * obatch + (long)col * ldo + row] = f2bf(v);
                }
            }
        }
    }
}

// ------------- softmax over rows of 256, fp32 in -> bf16 out ---------------
__global__ void softmax_k(const float* __restrict__ sim, u16* __restrict__ attn) {
    const int row = blockIdx.x * 4 + (threadIdx.x >> 6);
    const int lane = threadIdx.x & 63;
    float4 v = ((const float4*)(sim + (long)row * NS))[lane];
    float m = fmaxf(fmaxf(v.x, v.y), fmaxf(v.z, v.w));
    #pragma unroll
    for (int off = 32; off > 0; off >>= 1) m = fmaxf(m, __shfl_xor(m, off));
    float e0 = __expf(v.x - m), e1 = __expf(v.y - m), e2 = __expf(v.z - m), e3 = __expf(v.w - m);
    float s = e0 + e1 + e2 + e3;
    #pragma unroll
    for (int off = 32; off > 0; off >>= 1) s += __shfl_xor(s, off);
    float inv = 1.f / s;
    unsigned long long pk = (unsigned long long)f2bf(e0 * inv)
                          | ((unsigned long long)f2bf(e1 * inv) << 16)
                          | ((unsigned long long)f2bf(e2 * inv) << 32)
                          | ((unsigned long long)f2bf(e3 * inv) << 48);
    *(unsigned long long*)&attn[(long)row * NS + lane * 4] = pk;
}

extern "C" void kernel_launch(void* const* d_in, const int* in_sizes, int n_in,
                              void* d_out, int out_size, void* d_ws, size_t ws_size,
                              hipStream_t stream) {
    const float* x    = (const float*)d_in[0];
    const float* ctx  = (const float*)d_in[1];
    const float* gn_w = (const float*)d_in[2];
    const float* gn_b = (const float*)d_in[3];
    const float* ln_w = (const float*)d_in[4];
    const float* ln_b = (const float*)d_in[5];
    const float* wq   = (const float*)d_in[6];
    const float* bq   = (const float*)d_in[7];
    const float* wkv  = (const float*)d_in[8];
    const float* bkv  = (const float*)d_in[9];
    const float* wo   = (const float*)d_in[10];
    const float* bo   = (const float*)d_in[11];

    char* ws = (char*)d_ws;
    u16*   xnt  = (u16*)(ws + 0);             // 64 MB
    u16*   attn = (u16*)(ws + 67108864);      // 32 MB
    u16*   cn   = (u16*)(ws + 100663296);     //  6 MB
    u16*   kb_  = (u16*)(ws + 106954752);     //  4 MB  (k, row-major b,s,512)
    u16*   vb_  = (u16*)(ws + 111149056);     //  4 MB  (v, row-major b,s,512)
    u16*   Kq   = (u16*)(ws + 115343360);     //  4 MB  (K@wq, b,s,512)
    u16*   Vot  = (u16*)(ws + 119537664);     //  4 MB  ((V@wo^T)^T, b,c',s)
    u16*   wqtb = (u16*)(ws + 123731968);     // 512 KB (wq^T)
    u16*   wkvb = (u16*)(ws + 124256256);     // 1.5 MB
    u16*   wob  = (u16*)(ws + 125829120);     // 512 KB
    float* ga   = (float*)(ws + 126353408);
    float* gd   = ga + NB * DIM;
    float* kbias = (float*)(ws + 126418944);  // 16 KB
    float* sim  = (float*)d_out;              // first 64 MB of d_out, dead before final GEMM

    gn_stats<<<dim3(NB * 32), dim3(256), 0, stream>>>(x, gn_w, gn_b, ga, gd);
    gn_apply_t<<<dim3(2048, NB), dim3(256), 0, stream>>>(x, ga, gd, xnt);
    ln_ctx<<<dim3(NB * NS), dim3(256), 0, stream>>>(ctx, ln_w, ln_b, cn);
    cvt_weights<<<dim3(3072), dim3(256), 0, stream>>>(wq, wkv, wo, wqtb, wkvb, wob);

    // kv = cn(256x768) @ wkv^T -> k(b,s,512), v(b,s,512)
    gemm_nt<0><<<dim3(2 * 8, NB), dim3(256), 0, stream>>>(
        cn, wkvb, bkv, nullptr, kb_, vb_, NS, 2 * DIM, CTX,
        (long)NS * CTX, 0, (long)NS * DIM, DIM);
    // Kq = k @ wq  (B = wq^T stored [c][o])
    gemm_nt<3><<<dim3(2 * 4, NB), dim3(256), 0, stream>>>(
        kb_, wqtb, nullptr, nullptr, Kq, nullptr, NS, DIM, DIM,
        (long)NS * DIM, 0, (long)NS * DIM, DIM);
    kbias_k<<<dim3(NB * NS), dim3(256), 0, stream>>>(kb_, bq, kbias);
    // Vot = (v @ wo^T)^T : A=v, B=wo, write transposed [c'][s]
    gemm_nt<5><<<dim3(2 * 4, NB), dim3(256), 0, stream>>>(
        vb_, wob, nullptr, nullptr, Vot, nullptr, NS, DIM, DIM,
        (long)NS * DIM, 0, (long)DIM * NS, NS);
    // sim = (xnt @ Kq^T + kbias) * scale -> fp32 into d_out (scratch)
    gemm_nt<2><<<dim3(32 * 2, NB), dim3(256), 0, stream>>>(
        xnt, Kq, kbias, nullptr, sim, nullptr, HW, NS, DIM,
        (long)HW * DIM, (long)NS * DIM, (long)HW * NS, NS);
    softmax_k<<<dim3(16384), dim3(256), 0, stream>>>(sim, attn);
    // out = attn @ Vot^T + bo + x -> fp32 d_out (b,c,p), transposed epilogue
    gemm_nt<6><<<dim3(32 * 4, NB), dim3(256), 0, stream>>>(
        attn, Vot, bo, x, d_out, nullptr, HW, DIM, NS,
        (long)HW * NS, (long)DIM * NS, (long)DIM * HW, HW);
}

// Round 3
// 470.908 us; speedup vs baseline: 1.1740x; 1.0183x over previous
//
#include <hip/hip_runtime.h>

typedef unsigned short u16;
typedef __attribute__((ext_vector_type(8))) short short8;
typedef __attribute__((ext_vector_type(4))) float f32x4;

#define DIM 512
#define CTX 768
#define HW 4096
#define NB 16
#define NS 256
#define EPSV 1e-5f

__device__ inline u16 f2bf(float f) {
    union { float f; unsigned u; } x; x.f = f;
    unsigned r = x.u + 0x7fffu + ((x.u >> 16) & 1u);
    return (u16)(r >> 16);
}
__device__ inline float bf2f(u16 v) {
    union { unsigned u; float f; } x; x.u = (unsigned)v << 16; return x.f;
}

// ---------------- GroupNorm stats: per (b,g) mean/var -> per-channel a,d ----
__global__ void gn_stats(const float* __restrict__ x, const float* __restrict__ gn_w,
                         const float* __restrict__ gn_b, float* __restrict__ ga,
                         float* __restrict__ gd) {
    const int bg = blockIdx.x;           // b*32 + g
    const int b = bg >> 5, g = bg & 31;
    const float* base = x + ((long)b * DIM + g * 16) * HW;
    float s1 = 0.f, s2 = 0.f;
    const int tid = threadIdx.x;
    for (int i = tid; i < 16384; i += 256) {
        float4 v = ((const float4*)base)[i];
        s1 += v.x + v.y + v.z + v.w;
        s2 += v.x * v.x + v.y * v.y + v.z * v.z + v.w * v.w;
    }
    __shared__ float r1[256], r2[256];
    r1[tid] = s1; r2[tid] = s2; __syncthreads();
    for (int s = 128; s > 0; s >>= 1) {
        if (tid < s) { r1[tid] += r1[tid + s]; r2[tid] += r2[tid + s]; }
        __syncthreads();
    }
    __shared__ float mu_s, rs_s;
    if (tid == 0) {
        float mu = r1[0] * (1.f / 65536.f);
        float var = r2[0] * (1.f / 65536.f) - mu * mu;
        mu_s = mu; rs_s = rsqrtf(var + EPSV);
    }
    __syncthreads();
    if (tid < 16) {
        int c = g * 16 + tid;
        float aa = rs_s * gn_w[c];
        ga[b * DIM + c] = aa;
        gd[b * DIM + c] = gn_b[c] - mu_s * aa;
    }
}

// ------------- GN apply + transpose: x(b,c,p) -> xn_t(b,p,c) bf16 ----------
__global__ void gn_apply_t(const float* __restrict__ x, const float* __restrict__ ga,
                           const float* __restrict__ gd, u16* __restrict__ xnt) {
    const int b = blockIdx.y;
    const int c0 = (blockIdx.x & 15) * 32;
    const int p0 = (blockIdx.x >> 4) * 32;
    const int tx = threadIdx.x & 31, ty = threadIdx.x >> 5;  // 32 x 8
    __shared__ u16 tile[32][33];
    #pragma unroll
    for (int i = 0; i < 4; i++) {
        int c = c0 + ty + i * 8;
        float v = x[((long)b * DIM + c) * HW + p0 + tx];
        v = v * ga[b * DIM + c] + gd[b * DIM + c];
        tile[ty + i * 8][tx] = f2bf(v);
    }
    __syncthreads();
    #pragma unroll
    for (int i = 0; i < 4; i++) {
        int p = p0 + ty + i * 8;
        xnt[((long)b * HW + p) * DIM + c0 + tx] = tile[tx][ty + i * 8];
    }
}

// ------------- LayerNorm on context -> cn bf16 (b, s, 768) -----------------
__global__ void ln_ctx(const float* __restrict__ ctx, const float* __restrict__ ln_w,
                       const float* __restrict__ ln_b, u16* __restrict__ cn) {
    const int row = blockIdx.x;  // b*256 + s
    const int tid = threadIdx.x;
    const float* r = ctx + (long)row * CTX;
    float v[3]; float s1 = 0.f, s2 = 0.f;
    #pragma unroll
    for (int i = 0; i < 3; i++) { v[i] = r[tid + i * 256]; s1 += v[i]; s2 += v[i] * v[i]; }
    __shared__ float r1[256], r2[256];
    r1[tid] = s1; r2[tid] = s2; __syncthreads();
    for (int s = 128; s > 0; s >>= 1) {
        if (tid < s) { r1[tid] += r1[tid + s]; r2[tid] += r2[tid + s]; }
        __syncthreads();
    }
    __shared__ float mu_s, rs_s;
    if (tid == 0) {
        float mu = r1[0] * (1.f / 768.f);
        float var = r2[0] * (1.f / 768.f) - mu * mu;
        mu_s = mu; rs_s = rsqrtf(var + EPSV);
    }
    __syncthreads();
    #pragma unroll
    for (int i = 0; i < 3; i++) {
        int idx = tid + i * 256;
        cn[(long)row * CTX + idx] = f2bf((v[i] - mu_s) * rs_s * ln_w[idx] + ln_b[idx]);
    }
}

// ------------- weights fp32 -> bf16 (wq transposed: wqt[c][o] = wq[o][c]) ---
__global__ void cvt_weights(const float* __restrict__ wq, const float* __restrict__ wkv,
                            const float* __restrict__ wo, u16* __restrict__ wqtb,
                            u16* __restrict__ wkvb, u16* __restrict__ wob) {
    int i = blockIdx.x * 256 + threadIdx.x;
    if (i < 262144) {
        wqtb[(i & 511) * 512 + (i >> 9)] = f2bf(wq[i]);
        wob[i] = f2bf(wo[i]);
    }
    if (i < 786432) wkvb[i] = f2bf(wkv[i]);
}

// ------------- kbias[b*NS+s] = dot(k[b,s,:], bq) ---------------------------
__global__ void kbias_k(const u16* __restrict__ k, const float* __restrict__ bq,
                        float* __restrict__ kbias) {
    const int row = blockIdx.x;
    const int tid = threadIdx.x;
    const u16* r = k + (long)row * DIM;
    float s = bf2f(r[tid]) * bq[tid] + bf2f(r[tid + 256]) * bq[tid + 256];
    __shared__ float red[256];
    red[tid] = s; __syncthreads();
    for (int st = 128; st > 0; st >>= 1) {
        if (tid < st) red[tid] += red[tid + st];
        __syncthreads();
    }
    if (tid == 0) kbias[row] = red[0];
}

// ------------- generic 128x128 bf16 MFMA GEMM: C = A(MxK) * B(NxK)^T -------
// EPI 0: kv split (k / v row-major, +bkv)
// EPI 3: plain bf16 row-major
// EPI 5: bf16 transposed write (out[col][row])
template <int EPI>
__launch_bounds__(256, 2)
__global__ void gemm_nt(const u16* __restrict__ A, const u16* __restrict__ Bm,
                        const float* __restrict__ bias,
                        void* __restrict__ out0, void* __restrict__ out1,
                        int M, int N, int K, long batchA, long batchB,
                        long obatch, int ldo) {
    __shared__ u16 As[128][56];
    __shared__ u16 Bs[128][56];
    const int tid = threadIdx.x;
    const int lane = tid & 63;
    const int wave = tid >> 6;
    const int bb = blockIdx.y;
    const int tiles_n = N >> 7;
    const int m0 = (blockIdx.x / tiles_n) << 7;
    const int n0 = (blockIdx.x % tiles_n) << 7;
    const u16* Ab = A + (long)bb * batchA + (long)m0 * K;
    const u16* Bb = Bm + (long)bb * batchB + (long)n0 * K;

    const int sr = tid >> 2;          // 0..63
    const int sc = (tid & 3) << 3;    // 0,8,16,24
    const int l16 = lane & 15;
    const int quad = lane >> 4;
    const int wr = (wave >> 1) << 6;
    const int wc = (wave & 1) << 6;

    f32x4 acc[4][4] = {};

    for (int k0 = 0; k0 < K; k0 += 32) {
        __syncthreads();
        *(short8*)&As[sr][sc]      = *(const short8*)(Ab + (long)sr * K + k0 + sc);
        *(short8*)&As[sr + 64][sc] = *(const short8*)(Ab + (long)(sr + 64) * K + k0 + sc);
        *(short8*)&Bs[sr][sc]      = *(const short8*)(Bb + (long)sr * K + k0 + sc);
        *(short8*)&Bs[sr + 64][sc] = *(const short8*)(Bb + (long)(sr + 64) * K + k0 + sc);
        __syncthreads();
        short8 af[4], bfr[4];
        #pragma unroll
        for (int i = 0; i < 4; i++) af[i] = *(const short8*)&As[wr + i * 16 + l16][quad * 8];
        #pragma unroll
        for (int j = 0; j < 4; j++) bfr[j] = *(const short8*)&Bs[wc + j * 16 + l16][quad * 8];
        #pragma unroll
        for (int i = 0; i < 4; i++)
            #pragma unroll
            for (int j = 0; j < 4; j++)
                acc[i][j] = __builtin_amdgcn_mfma_f32_16x16x32_bf16(af[i], bfr[j], acc[i][j], 0, 0, 0);
    }

    #pragma unroll
    for (int i = 0; i < 4; i++) {
        #pragma unroll
        for (int r = 0; r < 4; r++) {
            const int row = m0 + wr + i * 16 + quad * 4 + r;
            #pragma unroll
            for (int j = 0; j < 4; j++) {
                const int col = n0 + wc + j * 16 + l16;
                float v = acc[i][j][r];
                if (EPI == 0) {
                    v += bias[col];
                    if (col < DIM) ((u16*)out0)[(long)bb * obatch + (long)row * ldo + col] = f2bf(v);
                    else           ((u16*)out1)[(long)bb * obatch + (long)row * ldo + (col - DIM)] = f2bf(v);
                } else if (EPI == 3) {
                    ((u16*)out0)[(long)bb * obatch + (long)row * ldo + col] = f2bf(v);
                } else {  // EPI == 5
                    ((u16*)out0)[(long)bb * obatch + (long)col * ldo + row] = f2bf(v);
                }
            }
        }
    }
}

// ------------- fused attention: S = xn@Kq^T, softmax, O = P@Vot^T ----------
// block: 512 thr (8 waves, 2m x 4n), 128 q-rows, full NS=256 cols.
// epilogue: out[b][c][p] = O[p][c] + bo[c] + x[b][c][p]  (LDS transpose)
__launch_bounds__(512, 2)
__global__ void flash_attn(const u16* __restrict__ xnt, const u16* __restrict__ Kq,
                           const u16* __restrict__ Vot, const float* __restrict__ kbias,
                           const float* __restrict__ bo, const float* __restrict__ x,
                           float* __restrict__ out) {
    // LDS: P 67584 | stage(As 128x56 + Bs 256x56)/Vs(128x264) 67584 | red 2048 | lbuf 16512
    __shared__ __align__(16) char fsm[153728];
    u16 (*P)[264]      = (u16(*)[264])(fsm);
    u16 (*As)[56]      = (u16(*)[56])(fsm + 67584);
    u16 (*Bs)[56]      = (u16(*)[56])(fsm + 67584 + 128 * 56 * 2);
    u16 (*Vs)[264]     = (u16(*)[264])(fsm + 67584);
    float (*red)[4]    = (float(*)[4])(fsm + 135168);
    float (*lbuf)[129] = (float(*)[129])(fsm + 137216);

    const int tid = threadIdx.x;
    const int lane = tid & 63;
    const int wave = tid >> 6;   // 0..7
    const int mw = wave >> 2;    // 0..1  (row group of 64)
    const int nw = wave & 3;     // 0..3  (col group of 64)
    const int l16 = lane & 15;
    const int quad = lane >> 4;
    const int b = blockIdx.y;
    const int m0 = blockIdx.x << 7;

    const u16* Ab = xnt + ((long)b * HW + m0) * DIM;
    const u16* Bb = Kq + (long)b * NS * DIM;

    // ---------------- S phase ----------------
    f32x4 acc[4][4] = {};
    for (int k0 = 0; k0 < DIM; k0 += 32) {
        __syncthreads();
        {
            const int r = tid >> 2, c = (tid & 3) << 3;
            *(short8*)&As[r][c] = *(const short8*)(Ab + (long)r * DIM + k0 + c);
            const int r2 = tid >> 1, c2 = (tid & 1) << 4;
            *(short8*)&Bs[r2][c2]     = *(const short8*)(Bb + (long)r2 * DIM + k0 + c2);
            *(short8*)&Bs[r2][c2 + 8] = *(const short8*)(Bb + (long)r2 * DIM + k0 + c2 + 8);
        }
        __syncthreads();
        short8 af[4], bfr[4];
        #pragma unroll
        for (int i = 0; i < 4; i++) af[i] = *(const short8*)&As[mw * 64 + i * 16 + l16][quad * 8];
        #pragma unroll
        for (int j = 0; j < 4; j++) bfr[j] = *(const short8*)&Bs[nw * 64 + j * 16 + l16][quad * 8];
        #pragma unroll
        for (int i = 0; i < 4; i++)
            #pragma unroll
            for (int j = 0; j < 4; j++)
                acc[i][j] = __builtin_amdgcn_mfma_f32_16x16x32_bf16(af[i], bfr[j], acc[i][j], 0, 0, 0);
    }

    // ---------------- softmax ----------------
    const float scale = 0.044194173824159216f;
    float kb[4];
    #pragma unroll
    for (int j = 0; j < 4; j++) kb[j] = kbias[b * NS + nw * 64 + j * 16 + l16];

    // scale+bias, per-wave row max, publish to red[row][nw]
    #pragma unroll
    for (int i = 0; i < 4; i++) {
        #pragma unroll
        for (int r = 0; r < 4; r++) {
            float m = -1e30f;
            #pragma unroll
            for (int j = 0; j < 4; j++) {
                float v = (acc[i][j][r] + kb[j]) * scale;
                acc[i][j][r] = v;
                m = fmaxf(m, v);
            }
            #pragma unroll
            for (int off = 1; off < 16; off <<= 1) m = fmaxf(m, __shfl_xor(m, off));
            if (l16 == 0) red[mw * 64 + i * 16 + quad * 4 + r][nw] = m;
        }
    }
    __syncthreads();
    // global row max, exp, per-wave row sum
    float rsum[4][4];
    #pragma unroll
    for (int i = 0; i < 4; i++) {
        #pragma unroll
        for (int r = 0; r < 4; r++) {
            const int row = mw * 64 + i * 16 + quad * 4 + r;
            float4 rv = *(const float4*)red[row];
            float gm = fmaxf(fmaxf(rv.x, rv.y), fmaxf(rv.z, rv.w));
            float s = 0.f;
            #pragma unroll
            for (int j = 0; j < 4; j++) {
                float e = __expf(acc[i][j][r] - gm);
                acc[i][j][r] = e;
                s += e;
            }
            #pragma unroll
            for (int off = 1; off < 16; off <<= 1) s += __shfl_xor(s, off);
            rsum[i][r] = s;
        }
    }
    __syncthreads();
    #pragma unroll
    for (int i = 0; i < 4; i++)
        #pragma unroll
        for (int r = 0; r < 4; r++)
            if (l16 == 0) red[mw * 64 + i * 16 + quad * 4 + r][nw] = rsum[i][r];
    __syncthreads();
    // normalize + write P (bf16) to LDS
    #pragma unroll
    for (int i = 0; i < 4; i++) {
        #pragma unroll
        for (int r = 0; r < 4; r++) {
            const int row = mw * 64 + i * 16 + quad * 4 + r;
            float4 sv = *(const float4*)red[row];
            float inv = 1.f / (sv.x + sv.y + sv.z + sv.w);
            #pragma unroll
            for (int j = 0; j < 4; j++)
                P[row][nw * 64 + j * 16 + l16] = f2bf(acc[i][j][r] * inv);
        }
    }

    // ---------------- PV phase: 4 chunks of 128 out-channels ----------------
    for (int nc = 0; nc < 4; nc++) {
        __syncthreads();   // P ready (nc=0) / prior chunk's Vs reads done
        {
            const u16* Vb = Vot + ((long)b * DIM + nc * 128) * NS;
            const int r = tid >> 2, c0 = (tid & 3) << 6;
            #pragma unroll
            for (int u = 0; u < 4; u++)
                *(short8*)&Vs[r][c0 + u * 8] = *(const short8*)(Vb + (long)r * NS + c0 + u * 8);
            #pragma unroll
            for (int u = 4; u < 8; u++)
                *(short8*)&Vs[r][c0 + u * 8] = *(const short8*)(Vb + (long)r * NS + c0 + u * 8);
        }
        __syncthreads();
        f32x4 oacc[4][2];
        #pragma unroll
        for (int i = 0; i < 4; i++)
            #pragma unroll
            for (int jj = 0; jj < 2; jj++)
                oacc[i][jj] = (f32x4){0.f, 0.f, 0.f, 0.f};
        #pragma unroll
        for (int kk = 0; kk < 8; kk++) {
            short8 pf[4], vf[2];
            #pragma unroll
            for (int i = 0; i < 4; i++)
                pf[i] = *(const short8*)&P[mw * 64 + i * 16 + l16][kk * 32 + quad * 8];
            #pragma unroll
            for (int jj = 0; jj < 2; jj++)
                vf[jj] = *(const short8*)&Vs[nw * 32 + jj * 16 + l16][kk * 32 + quad * 8];
            #pragma unroll
            for (int i = 0; i < 4; i++)
                #pragma unroll
                for (int jj = 0; jj < 2; jj++)
                    oacc[i][jj] = __builtin_amdgcn_mfma_f32_16x16x32_bf16(pf[i], vf[jj], oacc[i][jj], 0, 0, 0);
        }
        // epilogue: O chunk (128 p x 128 c), 4 passes of 32 cols
        #pragma unroll
        for (int t = 0; t < 4; t++) {
            if (t > 0) __syncthreads();   // prior lbuf reads done
            if (nw == t) {
                #pragma unroll
                for (int jj = 0; jj < 2; jj++)
                    #pragma unroll
                    for (int i = 0; i < 4; i++)
                        #pragma unroll
                        for (int r = 0; r < 4; r++)
                            lbuf[jj * 16 + l16][mw * 64 + i * 16 + quad * 4 + r] = oacc[i][jj][r];
            }
            __syncthreads();
            {
                const int cl = tid >> 4;          // 0..31
                const int p8 = (tid & 15) * 8;
                const int cg = nc * 128 + t * 32 + cl;
                const long idx = ((long)b * DIM + cg) * HW + m0 + p8;
                const float bv = bo[cg];
                float4 v0 = *(const float4*)&lbuf[cl][p8];
                float4 v1 = *(const float4*)&lbuf[cl][p8 + 4];
                float4 x0 = *(const float4*)&x[idx];
                float4 x1 = *(const float4*)&x[idx + 4];
                v0.x += x0.x + bv; v0.y += x0.y + bv; v0.z += x0.z + bv; v0.w += x0.w + bv;
                v1.x += x1.x + bv; v1.y += x1.y + bv; v1.z += x1.z + bv; v1.w += x1.w + bv;
                *(float4*)&out[idx] = v0;
                *(float4*)&out[idx + 4] = v1;
            }
        }
    }
}

extern "C" void kernel_launch(void* const* d_in, const int* in_sizes, int n_in,
                              void* d_out, int out_size, void* d_ws, size_t ws_size,
                              hipStream_t stream) {
    const float* x    = (const float*)d_in[0];
    const float* ctx  = (const float*)d_in[1];
    const float* gn_w = (const float*)d_in[2];
    const float* gn_b = (const float*)d_in[3];
    const float* ln_w = (const float*)d_in[4];
    const float* ln_b = (const float*)d_in[5];
    const float* wq   = (const float*)d_in[6];
    const float* bq   = (const float*)d_in[7];
    const float* wkv  = (const float*)d_in[8];
    const float* bkv  = (const float*)d_in[9];
    const float* wo   = (const float*)d_in[10];
    const float* bo   = (const float*)d_in[11];

    char* ws = (char*)d_ws;
    u16*   xnt  = (u16*)(ws + 0);             // 64 MB
    u16*   cn   = (u16*)(ws + 67108864);      //  6 MB
    u16*   kb_  = (u16*)(ws + 73400320);      //  4 MB  (k, row-major b,s,512)
    u16*   vb_  = (u16*)(ws + 77594624);      //  4 MB  (v, row-major b,s,512)
    u16*   Kq   = (u16*)(ws + 81788928);      //  4 MB  (K@wq, b,s,512)
    u16*   Vot  = (u16*)(ws + 85983232);      //  4 MB  ((V@wo^T)^T, b,c',s)
    u16*   wqtb = (u16*)(ws + 90177536);      // 512 KB (wq^T)
    u16*   wkvb = (u16*)(ws + 90701824);      // 1.5 MB
    u16*   wob  = (u16*)(ws + 92274688);      // 512 KB
    float* ga   = (float*)(ws + 92798976);
    float* gd   = ga + NB * DIM;
    float* kbias = (float*)(ws + 92864512);   // 16 KB

    gn_stats<<<dim3(NB * 32), dim3(256), 0, stream>>>(x, gn_w, gn_b, ga, gd);
    gn_apply_t<<<dim3(2048, NB), dim3(256), 0, stream>>>(x, ga, gd, xnt);
    ln_ctx<<<dim3(NB * NS), dim3(256), 0, stream>>>(ctx, ln_w, ln_b, cn);
    cvt_weights<<<dim3(3072), dim3(256), 0, stream>>>(wq, wkv, wo, wqtb, wkvb, wob);

    // kv = cn(256x768) @ wkv^T -> k(b,s,512), v(b,s,512)
    gemm_nt<0><<<dim3(2 * 8, NB), dim3(256), 0, stream>>>(
        cn, wkvb, bkv, kb_, vb_, NS, 2 * DIM, CTX,
        (long)NS * CTX, 0, (long)NS * DIM, DIM);
    // Kq = k @ wq  (B = wq^T stored [c][o])
    gemm_nt<3><<<dim3(2 * 4, NB), dim3(256), 0, stream>>>(
        kb_, wqtb, nullptr, Kq, nullptr, NS, DIM, DIM,
        (long)NS * DIM, 0, (long)NS * DIM, DIM);
    kbias_k<<<dim3(NB * NS), dim3(256), 0, stream>>>(kb_, bq, kbias);
    // Vot = (v @ wo^T)^T : A=v, B=wo, write transposed [c'][s]
    gemm_nt<5><<<dim3(2 * 4, NB), dim3(256), 0, stream>>>(
        vb_, wob, nullptr, Vot, nullptr, NS, DIM, DIM,
        (long)NS * DIM, 0, (long)DIM * NS, NS);
    // fused sim + softmax + PV + transpose + residual -> d_out (b,c,p) fp32
    flash_attn<<<dim3(32, NB), dim3(512), 0, stream>>>(
        xnt, Kq, Vot, kbias, bo, x, (float*)d_out);
}